// Round 10
// baseline (180.699 us; speedup 1.0000x reference)
//
#include <hip/hip_runtime.h>
#include <hip/hip_bf16.h>
#include <stdint.h>

// Problem constants (from reference): B=4096, D=768, N=8192, S=4
#define Bdim 4096
#define Ddim 768
#define Ndim 8192
#define Sdim 4

typedef __attribute__((ext_vector_type(4))) float floatx4;
typedef __attribute__((ext_vector_type(8))) int int8v;
typedef __attribute__((ext_vector_type(4))) int int4v;

// s_waitcnt immediates (gfx9 encoding: vmcnt[3:0]+[15:14], exp[6:4], lgkm[11:8])
#define WAIT_VM8 0x0F78  // vmcnt<=8, ignore exp/lgkm
#define WAIT_VM0 0x0F70  // vmcnt==0, ignore exp/lgkm

// fp32 -> bf16 round-to-nearest-even, as raw ushort
__device__ inline unsigned short f2bf(float f) {
  unsigned u = __builtin_bit_cast(unsigned, f);
  unsigned r = (u + 0x7fffu + ((u >> 16) & 1u)) >> 16;
  return (unsigned short)r;
}
__device__ inline float bf2f(unsigned short s) {
  return __builtin_bit_cast(float, (unsigned)s << 16);
}

// pack float4 -> 4x fp8 e4m3 (OCP on gfx950), HW RNE
__device__ inline int pack_fp8x4(float4 v) {
  int r = __builtin_amdgcn_cvt_pk_fp8_f32(v.x, v.y, 0, 0);  // low word
  r = __builtin_amdgcn_cvt_pk_fp8_f32(v.z, v.w, r, 1);      // high word
  return r;
}

// async global->LDS, 16B per lane (global_load_lds_dwordx4)
__device__ inline void async_copy16(const void* g, void* l) {
  __builtin_amdgcn_global_load_lds(
      (__attribute__((address_space(1))) void*)(g),
      (__attribute__((address_space(3))) void*)(l),
      16, 0, 0);
}

// ---------------------------------------------------------------------------
// Kernel 1: fp32 -> fp8 e4m3 quantization of batch_x and cat; zero the stats
// region; theta[s,b] = exp(batch_x[b].phi[s]) in fp32 (one wave per b).
// stats = [s4 (B) | denom (B) | numer (S*B)] floats
// ---------------------------------------------------------------------------
__global__ void convert_kernel(const float* __restrict__ x,
                               const float* __restrict__ cat,
                               const float* __restrict__ phi,
                               unsigned char* __restrict__ xq,
                               unsigned char* __restrict__ catq,
                               float* __restrict__ stats,
                               float* __restrict__ theta) {
  int gid = blockIdx.x * blockDim.x + threadIdx.x;
  int stride = gridDim.x * blockDim.x;
  const int nx4 = (Bdim * Ddim) / 4;
  const int nc4 = (Ndim * Ddim) / 4;
  for (int i = gid; i < nx4; i += stride)
    ((int*)xq)[i] = pack_fp8x4(((const float4*)x)[i]);
  for (int i = gid; i < nc4; i += stride)
    ((int*)catq)[i] = pack_fp8x4(((const float4*)cat)[i]);
  if (gid < 6 * Bdim) stats[gid] = 0.0f;

  // theta: one wave per batch row (fp32 — exact path, output-critical)
  int gw = gid >> 6;
  int lane = threadIdx.x & 63;
  if (gw < Bdim) {
    const float* xr = x + (size_t)gw * Ddim;
    float a0 = 0.f, a1 = 0.f, a2 = 0.f, a3 = 0.f;
    for (int d = lane; d < Ddim; d += 64) {
      float xv = xr[d];
      a0 = fmaf(xv, phi[d], a0);
      a1 = fmaf(xv, phi[Ddim + d], a1);
      a2 = fmaf(xv, phi[2 * Ddim + d], a2);
      a3 = fmaf(xv, phi[3 * Ddim + d], a3);
    }
#pragma unroll
    for (int off = 32; off > 0; off >>= 1) {
      a0 += __shfl_down(a0, off);
      a1 += __shfl_down(a1, off);
      a2 += __shfl_down(a2, off);
      a3 += __shfl_down(a3, off);
    }
    if (lane == 0) {
      theta[gw] = __expf(a0);
      theta[Bdim + gw] = __expf(a1);
      theta[2 * Bdim + gw] = __expf(a2);
      theta[3 * Bdim + gw] = __expf(a3);
    }
  }
}

// ---------------------------------------------------------------------------
// Kernel 2: MX-scaled fp8 MFMA GEMM  con[n,b] = sum_k cat[n,k]*x[b,k]
// R10: double-buffered LDS ping-pong (2 x 32KB = 64KB; still 2 blocks/CU —
// occupancy was already reg-capped at ~2-3, so dbuf is free) + RAW
// s_barrier with manual s_waitcnt vmcnt(8): next tile's 8 global_load_lds
// stay IN FLIGHT across the barrier (AITER-style; kills R9's per-iter
// vmcnt(0) drain, which at 6 K-iters serialized ~900cyc load latency into
// every iteration -> MfmaUtil 15%).
// Hazards: loads into buf X at iter k+1 are gated by iter k's trailing
// barrier (all reads of buf X done); waitcnt vmcnt(8) before the leading
// barrier completes exactly the current tile's (older) 8 loads; last iter
// waits vmcnt(0). Fully unrolled so waitcnt immediates are constants.
// Layout/math identical to R9 (verified: absmax 0.0039, conflicts 3.15M):
// granule-interleaved LDS (slot = (r>>3)*64 + g*8 + (r&7)), fragment
// k = quad*32+j, unit E8M0 scales (0x7F), natural x-major grid.
// Epilogue: bf16 C-write + fused pow4.
// ---------------------------------------------------------------------------
__global__ __launch_bounds__(256) void gemm_bt_kernel(
    const unsigned char* __restrict__ A,    // cat fp8 [Ndim, Ddim]
    const unsigned char* __restrict__ Bm,   // x   fp8 [Bdim, Ddim]
    unsigned short* __restrict__ C,         // con bf16 [Ndim, Bdim]
    float* __restrict__ s4) {               // [Bdim] p4 column sums
  __shared__ unsigned char As[2][128 * 128];  // ping-pong, 16 KB each
  __shared__ unsigned char Bs[2][128 * 128];

  const int tid = threadIdx.x;
  const int wave = tid >> 6;
  const int lane = tid & 63;
  const int quad = lane >> 4;
  const int l16 = lane & 15;
  const int wm = (wave & 1) * 64;
  const int wn = (wave >> 1) * 64;
  const int m0 = blockIdx.x * 128;
  const int n0 = blockIdx.y * 128;

  floatx4 acc[4][4];
#pragma unroll
  for (int i = 0; i < 4; ++i)
#pragma unroll
    for (int j = 0; j < 4; ++j) acc[i][j] = (floatx4){0.f, 0.f, 0.f, 0.f};

  // staging: 1024 granule-slots per operand per K-iter; slot p holds
  // (row = (p>>6)*8 + (p&7), granule g = (p>>3)&7); 4 slots per thread.
  const unsigned char* a_src[4];
  const unsigned char* b_src[4];
#pragma unroll
  for (int i = 0; i < 4; ++i) {
    int p = tid + 256 * i;
    int row = ((p >> 6) << 3) + (p & 7);
    int colb = ((p >> 3) & 7) * 16;
    a_src[i] = A + (size_t)(m0 + row) * Ddim + colb;
    b_src[i] = Bm + (size_t)(n0 + row) * Ddim + colb;
  }

  // prologue: stage tile 0 into buffer 0 (8 loads in flight)
#pragma unroll
  for (int i = 0; i < 4; ++i) {
    async_copy16(a_src[i], As[0] + (tid + 256 * i) * 16);
    async_copy16(b_src[i], Bs[0] + (tid + 256 * i) * 16);
  }

#pragma unroll
  for (int kk = 0; kk < 6; ++kk) {
    const int p = kk & 1;
    if (kk < 5) {
      const int k0 = (kk + 1) * 128;
      // prefetch next tile into the other buffer (8 newer loads)
#pragma unroll
      for (int i = 0; i < 4; ++i) {
        async_copy16(a_src[i] + k0, As[1 - p] + (tid + 256 * i) * 16);
        async_copy16(b_src[i] + k0, Bs[1 - p] + (tid + 256 * i) * 16);
      }
      __builtin_amdgcn_s_waitcnt(WAIT_VM8);  // current tile done; prefetch stays in flight
    } else {
      __builtin_amdgcn_s_waitcnt(WAIT_VM0);  // last tile: drain
    }
    __builtin_amdgcn_s_barrier();  // raw: no compiler vmcnt(0) drain

    // fragment: row r, k = quad*32..+31 = granules 2q,2q+1 ->
    // byte (r>>3)*1024 + quad*256 + (r&7)*16, and +128.
    int8v af[4], bf[4];
#pragma unroll
    for (int mi = 0; mi < 4; ++mi) {
      int r = wm + mi * 16 + l16;
      int base = ((r >> 3) << 10) + quad * 256 + (r & 7) * 16;
      int4v lo = *(const int4v*)(As[p] + base);
      int4v hi = *(const int4v*)(As[p] + base + 128);
      af[mi] = __builtin_shufflevector(lo, hi, 0, 1, 2, 3, 4, 5, 6, 7);
    }
#pragma unroll
    for (int ni = 0; ni < 4; ++ni) {
      int r = wn + ni * 16 + l16;
      int base = ((r >> 3) << 10) + quad * 256 + (r & 7) * 16;
      int4v lo = *(const int4v*)(Bs[p] + base);
      int4v hi = *(const int4v*)(Bs[p] + base + 128);
      bf[ni] = __builtin_shufflevector(lo, hi, 0, 1, 2, 3, 4, 5, 6, 7);
    }
#pragma unroll
    for (int mi = 0; mi < 4; ++mi)
#pragma unroll
      for (int ni = 0; ni < 4; ++ni)
        acc[mi][ni] = __builtin_amdgcn_mfma_scale_f32_16x16x128_f8f6f4(
            af[mi], bf[ni], acc[mi][ni], 0, 0,  // cbsz=0 (fp8), blgp=0 (fp8)
            0, 0x7f7f7f7f,                      // scale A: E8M0 1.0
            0, 0x7f7f7f7f);                     // scale B: E8M0 1.0

    __builtin_amdgcn_s_barrier();  // all reads of buf[p] done before it is
                                   // overwritten at iter kk+2
  }

  // C/D layout (16x16, shape-determined incl. f8f6f4): col = lane&15,
  // row = quad*4 + reg. Fused pow4 epilogue unchanged (R6-R9 verified).
  float cs4[4] = {0.f, 0.f, 0.f, 0.f};
#pragma unroll
  for (int mi = 0; mi < 4; ++mi)
#pragma unroll
    for (int ni = 0; ni < 4; ++ni) {
      int row = m0 + wm + mi * 16 + quad * 4;
      int col = n0 + wn + ni * 16 + l16;
#pragma unroll
      for (int rr = 0; rr < 4; ++rr) {
        float cv = acc[mi][ni][rr];
        C[(size_t)(row + rr) * Bdim + col] = f2bf(cv);
        float c2 = cv * cv;
        cs4[ni] += c2 * c2;
      }
    }
#pragma unroll
  for (int ni = 0; ni < 4; ++ni) {
    float v = cs4[ni];
    v += __shfl_xor(v, 16);
    v += __shfl_xor(v, 32);
    if (quad == 0) atomicAdd(&s4[n0 + wn + ni * 16 + l16], v);
  }
}

// ---------------------------------------------------------------------------
// Kernel 3: denom[b] += sum exp(con/norm4); numer[s,b] += y-masked sum.
// norm4 >= max|con| so logits are in [-1,1]: no max-subtraction needed.
// Thread owns 4 consecutive columns (ushort4 loads, 512B/wave coalesced).
// Stream ordering (not fences) is the cross-kernel coherence path (R3/R5).
// ---------------------------------------------------------------------------
__global__ void expsum_kernel(const unsigned short* __restrict__ con,
                              const float* __restrict__ s4,
                              const int* __restrict__ y,
                              float* __restrict__ denom,
                              float* __restrict__ numer) {
  int col0 = blockIdx.x * 1024 + threadIdx.x * 4;
  int n0 = blockIdx.y * 64;
  int src = n0 / (Ndim / Sdim);  // 64-row chunk is always within one source

  float4 s = *(const float4*)(s4 + col0);
  float inv0 = 1.0f / fmaxf(sqrtf(sqrtf(s.x)), 1e-12f);
  float inv1 = 1.0f / fmaxf(sqrtf(sqrtf(s.y)), 1e-12f);
  float inv2 = 1.0f / fmaxf(sqrtf(sqrtf(s.z)), 1e-12f);
  float inv3 = 1.0f / fmaxf(sqrtf(sqrtf(s.w)), 1e-12f);

  const unsigned short* p = con + (size_t)n0 * Bdim + col0;
  float d0 = 0.f, d1 = 0.f, d2 = 0.f, d3 = 0.f;
  float m0 = 0.f, m1 = 0.f, m2 = 0.f, m3 = 0.f;
#pragma unroll 8
  for (int i = 0; i < 64; ++i) {
    ushort4 v = *(const ushort4*)(p + (size_t)i * Bdim);
    float yv = (float)y[n0 + i];  // wave-uniform, cached
    float e0 = __expf(bf2f(v.x) * inv0);
    float e1 = __expf(bf2f(v.y) * inv1);
    float e2 = __expf(bf2f(v.z) * inv2);
    float e3 = __expf(bf2f(v.w) * inv3);
    d0 += e0; d1 += e1; d2 += e2; d3 += e3;
    m0 += e0 * yv; m1 += e1 * yv; m2 += e2 * yv; m3 += e3 * yv;
  }
  atomicAdd(&denom[col0 + 0], d0);
  atomicAdd(&denom[col0 + 1], d1);
  atomicAdd(&denom[col0 + 2], d2);
  atomicAdd(&denom[col0 + 3], d3);
  float* np = numer + (size_t)src * Bdim + col0;
  atomicAdd(np + 0, m0);
  atomicAdd(np + 1, m1);
  atomicAdd(np + 2, m2);
  atomicAdd(np + 3, m3);
}

// ---------------------------------------------------------------------------
// Kernel 4 (tiny): out[b] = sigmoid(sum_s numer[s,b]*theta[s,b]/denom[b]+bias)
// ---------------------------------------------------------------------------
__global__ void finalize_kernel(const float* __restrict__ denom,
                                const float* __restrict__ numer,
                                const float* __restrict__ theta,
                                const float* __restrict__ bias,
                                float* __restrict__ out) {
  int b = blockIdx.x * 256 + threadIdx.x;
  float acc = 0.f;
#pragma unroll
  for (int si = 0; si < Sdim; ++si)
    acc += numer[si * Bdim + b] * theta[si * Bdim + b];
  float z = acc / denom[b] + bias[0];
  out[b] = 1.0f / (1.0f + __expf(-z));
}

// ---------------------------------------------------------------------------
// Workspace layout (bytes):
//   catq  : Ndim*Ddim     =  6,291,456   (fp8)
//   xq    : Bdim*Ddim     =  3,145,728   (fp8)
//   con   : Ndim*Bdim*2   = 67,108,864   (bf16)
//   stats : 6*Bdim*4      =     98,304   (s4 | denom | numer)
//   theta : Sdim*Bdim*4   =     65,536
//   total ≈ 76.7 MB
// ---------------------------------------------------------------------------
extern "C" void kernel_launch(void* const* d_in, const int* in_sizes, int n_in,
                              void* d_out, int out_size, void* d_ws,
                              size_t ws_size, hipStream_t stream) {
  const float* batch_x = (const float*)d_in[0];
  const float* cat = (const float*)d_in[1];
  const int* y = (const int*)d_in[2];
  const float* phi = (const float*)d_in[3];
  const float* bias = (const float*)d_in[4];
  float* out = (float*)d_out;

  char* ws = (char*)d_ws;
  unsigned char* catq = (unsigned char*)ws;
  unsigned char* xq = catq + (size_t)Ndim * Ddim;
  unsigned short* con = (unsigned short*)(xq + (size_t)Bdim * Ddim);
  float* stats = (float*)(con + (size_t)Ndim * Bdim);
  float* s4 = stats;
  float* denom = s4 + Bdim;
  float* numer = denom + Bdim;        // Sdim * Bdim
  float* theta = stats + 6 * Bdim;    // Sdim * Bdim

  convert_kernel<<<2048, 256, 0, stream>>>(batch_x, cat, phi, xq, catq, stats,
                                           theta);

  dim3 g2(Ndim / 128, Bdim / 128);
  gemm_bt_kernel<<<g2, 256, 0, stream>>>(catq, xq, con, s4);

  dim3 g3(Bdim / 1024, Ndim / 64);
  expsum_kernel<<<g3, 256, 0, stream>>>(con, s4, y, denom, numer);

  finalize_kernel<<<Bdim / 256, 256, 0, stream>>>(denom, numer, theta, bias,
                                                  out);
}

// Round 11
// 157.057 us; speedup vs baseline: 1.1505x; 1.1505x over previous
//
#include <hip/hip_runtime.h>
#include <hip/hip_bf16.h>
#include <stdint.h>

// Problem constants (from reference): B=4096, D=768, N=8192, S=4
#define Bdim 4096
#define Ddim 768
#define Ndim 8192
#define Sdim 4

typedef __attribute__((ext_vector_type(4))) float floatx4;
typedef __attribute__((ext_vector_type(8))) int int8v;
typedef __attribute__((ext_vector_type(4))) int int4v;

// pack float4 -> 4x fp8 e4m3 (OCP on gfx950), HW RNE
__device__ inline int pack_fp8x4(float4 v) {
  int r = __builtin_amdgcn_cvt_pk_fp8_f32(v.x, v.y, 0, 0);  // low word
  r = __builtin_amdgcn_cvt_pk_fp8_f32(v.z, v.w, r, 1);      // high word
  return r;
}

// async global->LDS, 16B per lane (global_load_lds_dwordx4)
__device__ inline void async_copy16(const void* g, void* l) {
  __builtin_amdgcn_global_load_lds(
      (__attribute__((address_space(1))) void*)(g),
      (__attribute__((address_space(3))) void*)(l),
      16, 0, 0);
}

// ---------------------------------------------------------------------------
// Kernel 1: fp32 -> fp8 e4m3 quantization of batch_x and cat; zero the stats
// region; theta[s,b] = exp(batch_x[b].phi[s]) in fp32 (one wave per b).
// stats = [s4 (B) | denom (B) | numer (S*B)] floats
// ---------------------------------------------------------------------------
__global__ void convert_kernel(const float* __restrict__ x,
                               const float* __restrict__ cat,
                               const float* __restrict__ phi,
                               unsigned char* __restrict__ xq,
                               unsigned char* __restrict__ catq,
                               float* __restrict__ stats,
                               float* __restrict__ theta) {
  int gid = blockIdx.x * blockDim.x + threadIdx.x;
  int stride = gridDim.x * blockDim.x;
  const int nx4 = (Bdim * Ddim) / 4;
  const int nc4 = (Ndim * Ddim) / 4;
  for (int i = gid; i < nx4; i += stride)
    ((int*)xq)[i] = pack_fp8x4(((const float4*)x)[i]);
  for (int i = gid; i < nc4; i += stride)
    ((int*)catq)[i] = pack_fp8x4(((const float4*)cat)[i]);
  if (gid < 6 * Bdim) stats[gid] = 0.0f;

  // theta: one wave per batch row (fp32 — exact path, output-critical)
  int gw = gid >> 6;
  int lane = threadIdx.x & 63;
  if (gw < Bdim) {
    const float* xr = x + (size_t)gw * Ddim;
    float a0 = 0.f, a1 = 0.f, a2 = 0.f, a3 = 0.f;
    for (int d = lane; d < Ddim; d += 64) {
      float xv = xr[d];
      a0 = fmaf(xv, phi[d], a0);
      a1 = fmaf(xv, phi[Ddim + d], a1);
      a2 = fmaf(xv, phi[2 * Ddim + d], a2);
      a3 = fmaf(xv, phi[3 * Ddim + d], a3);
    }
#pragma unroll
    for (int off = 32; off > 0; off >>= 1) {
      a0 += __shfl_down(a0, off);
      a1 += __shfl_down(a1, off);
      a2 += __shfl_down(a2, off);
      a3 += __shfl_down(a3, off);
    }
    if (lane == 0) {
      theta[gw] = __expf(a0);
      theta[Bdim + gw] = __expf(a1);
      theta[2 * Bdim + gw] = __expf(a2);
      theta[3 * Bdim + gw] = __expf(a3);
    }
  }
}

// ---------------------------------------------------------------------------
// Kernel 2: MX-scaled fp8 MFMA GEMM  con[n,b] = sum_k cat[n,k]*x[b,k]
// K-loop is R9-EXACT (62.7us measured; R10's dbuf cost occupancy 26->18.5%
// and regressed — do not trade resident blocks for explicit pipelining):
// single 16KB buffer per operand, 6 iters of K=128, 2 barriers/iter,
// granule-interleaved LDS (slot = (r>>3)*64 + g*8 + (r&7); conflicts 3.15M
// = b128 structural), fragment k = quad*32+j, unit E8M0 scales.
// NEW (R11): con stored as fp8 e4m3 in [N/4, B, 4] row-group-interleaved
// layout — each lane's 4 acc rows (quad*4+0..3, one col) pack via
// cvt_pk_fp8_f32 x2 into ONE dword store (16 dword-stores/thread vs 64
// short-stores; 64B contiguous per quad; WRITE_SIZE halves to ~34MB).
// pow4 stays on exact fp32 acc. Natural x-major grid (R4 lesson).
// ---------------------------------------------------------------------------
__global__ __launch_bounds__(256) void gemm_bt_kernel(
    const unsigned char* __restrict__ A,    // cat fp8 [Ndim, Ddim]
    const unsigned char* __restrict__ Bm,   // x   fp8 [Bdim, Ddim]
    unsigned int* __restrict__ Cw,          // con fp8 [Ndim/4, Bdim, 4] as u32
    float* __restrict__ s4) {               // [Bdim] p4 column sums
  __shared__ unsigned char As[128 * 128];  // 16 KB, granule-interleaved
  __shared__ unsigned char Bs[128 * 128];  // 16 KB

  const int tid = threadIdx.x;
  const int wave = tid >> 6;
  const int lane = tid & 63;
  const int quad = lane >> 4;
  const int l16 = lane & 15;
  const int wm = (wave & 1) * 64;
  const int wn = (wave >> 1) * 64;
  const int m0 = blockIdx.x * 128;
  const int n0 = blockIdx.y * 128;

  floatx4 acc[4][4];
#pragma unroll
  for (int i = 0; i < 4; ++i)
#pragma unroll
    for (int j = 0; j < 4; ++j) acc[i][j] = (floatx4){0.f, 0.f, 0.f, 0.f};

  // staging: 1024 granule-slots per operand per K-iter; slot p holds
  // (row = (p>>6)*8 + (p&7), granule g = (p>>3)&7); 4 slots per thread.
  const unsigned char* a_src[4];
  const unsigned char* b_src[4];
#pragma unroll
  for (int i = 0; i < 4; ++i) {
    int p = tid + 256 * i;
    int row = ((p >> 6) << 3) + (p & 7);
    int colb = ((p >> 3) & 7) * 16;
    a_src[i] = A + (size_t)(m0 + row) * Ddim + colb;
    b_src[i] = Bm + (size_t)(n0 + row) * Ddim + colb;
  }

  for (int k0 = 0; k0 < Ddim; k0 += 128) {
#pragma unroll
    for (int i = 0; i < 4; ++i) {
      async_copy16(a_src[i] + k0, As + (tid + 256 * i) * 16);
      async_copy16(b_src[i] + k0, Bs + (tid + 256 * i) * 16);
    }
    __syncthreads();  // drains vmcnt before barrier

    // fragment: row r, k = quad*32..+31 = granules 2q,2q+1 ->
    // byte (r>>3)*1024 + quad*256 + (r&7)*16, and +128.
    int8v af[4], bf[4];
#pragma unroll
    for (int mi = 0; mi < 4; ++mi) {
      int r = wm + mi * 16 + l16;
      int base = ((r >> 3) << 10) + quad * 256 + (r & 7) * 16;
      int4v lo = *(const int4v*)(As + base);
      int4v hi = *(const int4v*)(As + base + 128);
      af[mi] = __builtin_shufflevector(lo, hi, 0, 1, 2, 3, 4, 5, 6, 7);
    }
#pragma unroll
    for (int ni = 0; ni < 4; ++ni) {
      int r = wn + ni * 16 + l16;
      int base = ((r >> 3) << 10) + quad * 256 + (r & 7) * 16;
      int4v lo = *(const int4v*)(Bs + base);
      int4v hi = *(const int4v*)(Bs + base + 128);
      bf[ni] = __builtin_shufflevector(lo, hi, 0, 1, 2, 3, 4, 5, 6, 7);
    }
#pragma unroll
    for (int mi = 0; mi < 4; ++mi)
#pragma unroll
      for (int ni = 0; ni < 4; ++ni)
        acc[mi][ni] = __builtin_amdgcn_mfma_scale_f32_16x16x128_f8f6f4(
            af[mi], bf[ni], acc[mi][ni], 0, 0,  // cbsz=0 (fp8), blgp=0 (fp8)
            0, 0x7f7f7f7f,                      // scale A: E8M0 1.0
            0, 0x7f7f7f7f);                     // scale B: E8M0 1.0
    __syncthreads();
  }

  // C/D layout (16x16): col = lane&15, row = quad*4 + reg [verified].
  // acc[..][0..3] = rows 4g..4g+3 of one column -> exactly one packed u32
  // at word index g*Bdim + col of the [N/4, B, 4] layout.
  float cs4[4] = {0.f, 0.f, 0.f, 0.f};
#pragma unroll
  for (int mi = 0; mi < 4; ++mi)
#pragma unroll
    for (int ni = 0; ni < 4; ++ni) {
      int g = (m0 + wm + mi * 16) / 4 + quad;  // n-group index
      int col = n0 + wn + ni * 16 + l16;
      floatx4 a = acc[mi][ni];
      int w = __builtin_amdgcn_cvt_pk_fp8_f32(a[0], a[1], 0, 0);
      w = __builtin_amdgcn_cvt_pk_fp8_f32(a[2], a[3], w, 1);
      Cw[(size_t)g * Bdim + col] = (unsigned int)w;
#pragma unroll
      for (int rr = 0; rr < 4; ++rr) {
        float c2 = a[rr] * a[rr];
        cs4[ni] += c2 * c2;  // pow4 on exact fp32 acc
      }
    }
#pragma unroll
  for (int ni = 0; ni < 4; ++ni) {
    float v = cs4[ni];
    v += __shfl_xor(v, 16);
    v += __shfl_xor(v, 32);
    if (quad == 0) atomicAdd(&s4[n0 + wn + ni * 16 + l16], v);
  }
}

// ---------------------------------------------------------------------------
// Kernel 3: denom[b] += sum exp(con/norm4); numer[s,b] += y-masked sum.
// Reads fp8 [N/4, B, 4] con: one u32 = 4 n-elements per thread per iter,
// lanes on consecutive b -> 256B/wave coalesced; y via wave-uniform int4.
// norm4 >= max|fp32 con| and fp8 quantization adds <=~7% -> logits <= ~1.07:
// still no max-subtraction needed. grid (16, 32): block = 256 cols x 64
// n-groups (256 n, wholly inside one source). 2 atomics per thread.
// ---------------------------------------------------------------------------
__global__ void expsum_kernel(const unsigned int* __restrict__ conq,
                              const float* __restrict__ s4,
                              const int* __restrict__ y,
                              float* __restrict__ denom,
                              float* __restrict__ numer) {
  int b = blockIdx.x * 256 + threadIdx.x;
  int g0 = blockIdx.y * 64;                 // n-group range [g0, g0+64)
  int src = (g0 * 4) / (Ndim / Sdim);       // uniform per block

  float inv = 1.0f / fmaxf(sqrtf(sqrtf(s4[b])), 1e-12f);
  const unsigned int* p = conq + (size_t)g0 * Bdim + b;
  float dsum = 0.f, nsum = 0.f;
#pragma unroll 4
  for (int i = 0; i < 64; ++i) {
    unsigned int w = p[(size_t)i * Bdim];
    int4 yv = *(const int4*)(y + 4 * (g0 + i));  // wave-uniform
    float e0 = __expf(__builtin_amdgcn_cvt_f32_fp8(w, 0) * inv);
    float e1 = __expf(__builtin_amdgcn_cvt_f32_fp8(w, 1) * inv);
    float e2 = __expf(__builtin_amdgcn_cvt_f32_fp8(w, 2) * inv);
    float e3 = __expf(__builtin_amdgcn_cvt_f32_fp8(w, 3) * inv);
    dsum += e0 + e1 + e2 + e3;
    nsum += e0 * (float)yv.x + e1 * (float)yv.y + e2 * (float)yv.z +
            e3 * (float)yv.w;
  }
  atomicAdd(&denom[b], dsum);
  atomicAdd(&numer[src * Bdim + b], nsum);
}

// ---------------------------------------------------------------------------
// Kernel 4 (tiny): out[b] = sigmoid(sum_s numer[s,b]*theta[s,b]/denom[b]+bias)
// ---------------------------------------------------------------------------
__global__ void finalize_kernel(const float* __restrict__ denom,
                                const float* __restrict__ numer,
                                const float* __restrict__ theta,
                                const float* __restrict__ bias,
                                float* __restrict__ out) {
  int b = blockIdx.x * 256 + threadIdx.x;
  float acc = 0.f;
#pragma unroll
  for (int si = 0; si < Sdim; ++si)
    acc += numer[si * Bdim + b] * theta[si * Bdim + b];
  float z = acc / denom[b] + bias[0];
  out[b] = 1.0f / (1.0f + __expf(-z));
}

// ---------------------------------------------------------------------------
// Workspace layout (bytes):
//   catq  : Ndim*Ddim     =  6,291,456   (fp8)
//   xq    : Bdim*Ddim     =  3,145,728   (fp8)
//   conq  : Ndim*Bdim     = 33,554,432   (fp8, [N/4, B, 4] interleaved)
//   stats : 6*Bdim*4      =     98,304   (s4 | denom | numer)
//   theta : Sdim*Bdim*4   =     65,536
//   total ≈ 43.2 MB
// ---------------------------------------------------------------------------
extern "C" void kernel_launch(void* const* d_in, const int* in_sizes, int n_in,
                              void* d_out, int out_size, void* d_ws,
                              size_t ws_size, hipStream_t stream) {
  const float* batch_x = (const float*)d_in[0];
  const float* cat = (const float*)d_in[1];
  const int* y = (const int*)d_in[2];
  const float* phi = (const float*)d_in[3];
  const float* bias = (const float*)d_in[4];
  float* out = (float*)d_out;

  char* ws = (char*)d_ws;
  unsigned char* catq = (unsigned char*)ws;
  unsigned char* xq = catq + (size_t)Ndim * Ddim;
  unsigned int* conq = (unsigned int*)(xq + (size_t)Bdim * Ddim);
  float* stats = (float*)((unsigned char*)conq + (size_t)Ndim * Bdim);
  float* s4 = stats;
  float* denom = s4 + Bdim;
  float* numer = denom + Bdim;        // Sdim * Bdim
  float* theta = stats + 6 * Bdim;    // Sdim * Bdim

  convert_kernel<<<2048, 256, 0, stream>>>(batch_x, cat, phi, xq, catq, stats,
                                           theta);

  dim3 g2(Ndim / 128, Bdim / 128);
  gemm_bt_kernel<<<g2, 256, 0, stream>>>(catq, xq, conq, s4);

  dim3 g3(Bdim / 256, 32);
  expsum_kernel<<<g3, 256, 0, stream>>>(conq, s4, y, denom, numer);

  finalize_kernel<<<Bdim / 256, 256, 0, stream>>>(denom, numer, theta, bias,
                                                  out);
}

// Round 12
// 157.034 us; speedup vs baseline: 1.1507x; 1.0001x over previous
//
#include <hip/hip_runtime.h>
#include <hip/hip_bf16.h>
#include <stdint.h>

// Problem constants (from reference): B=4096, D=768, N=8192, S=4
#define Bdim 4096
#define Ddim 768
#define Ndim 8192
#define Sdim 4

typedef __attribute__((ext_vector_type(4))) float floatx4;
typedef __attribute__((ext_vector_type(8))) int int8v;
typedef __attribute__((ext_vector_type(4))) int int4v;

// pack float4 -> 4x fp8 e4m3 (OCP on gfx950), HW RNE
__device__ inline int pack_fp8x4(float4 v) {
  int r = __builtin_amdgcn_cvt_pk_fp8_f32(v.x, v.y, 0, 0);  // low word
  r = __builtin_amdgcn_cvt_pk_fp8_f32(v.z, v.w, r, 1);      // high word
  return r;
}

// async global->LDS, 16B per lane (global_load_lds_dwordx4)
__device__ inline void async_copy16(const void* g, void* l) {
  __builtin_amdgcn_global_load_lds(
      (__attribute__((address_space(1))) void*)(g),
      (__attribute__((address_space(3))) void*)(l),
      16, 0, 0);
}

// ---------------------------------------------------------------------------
// Kernel 1: fp32 -> fp8 e4m3 quantization of batch_x and cat; zero the stats
// region; theta[s,b] = exp(batch_x[b].phi[s]) in fp32 (one wave per b).
// stats = [s4 (B) | denom (B) | numer (S*B)] floats
// ---------------------------------------------------------------------------
__global__ void convert_kernel(const float* __restrict__ x,
                               const float* __restrict__ cat,
                               const float* __restrict__ phi,
                               unsigned char* __restrict__ xq,
                               unsigned char* __restrict__ catq,
                               float* __restrict__ stats,
                               float* __restrict__ theta) {
  int gid = blockIdx.x * blockDim.x + threadIdx.x;
  int stride = gridDim.x * blockDim.x;
  const int nx4 = (Bdim * Ddim) / 4;
  const int nc4 = (Ndim * Ddim) / 4;
  for (int i = gid; i < nx4; i += stride)
    ((int*)xq)[i] = pack_fp8x4(((const float4*)x)[i]);
  for (int i = gid; i < nc4; i += stride)
    ((int*)catq)[i] = pack_fp8x4(((const float4*)cat)[i]);
  if (gid < 6 * Bdim) stats[gid] = 0.0f;

  // theta: one wave per batch row (fp32 — exact path, output-critical)
  int gw = gid >> 6;
  int lane = threadIdx.x & 63;
  if (gw < Bdim) {
    const float* xr = x + (size_t)gw * Ddim;
    float a0 = 0.f, a1 = 0.f, a2 = 0.f, a3 = 0.f;
    for (int d = lane; d < Ddim; d += 64) {
      float xv = xr[d];
      a0 = fmaf(xv, phi[d], a0);
      a1 = fmaf(xv, phi[Ddim + d], a1);
      a2 = fmaf(xv, phi[2 * Ddim + d], a2);
      a3 = fmaf(xv, phi[3 * Ddim + d], a3);
    }
#pragma unroll
    for (int off = 32; off > 0; off >>= 1) {
      a0 += __shfl_down(a0, off);
      a1 += __shfl_down(a1, off);
      a2 += __shfl_down(a2, off);
      a3 += __shfl_down(a3, off);
    }
    if (lane == 0) {
      theta[gw] = __expf(a0);
      theta[Bdim + gw] = __expf(a1);
      theta[2 * Bdim + gw] = __expf(a2);
      theta[3 * Bdim + gw] = __expf(a3);
    }
  }
}

// ---------------------------------------------------------------------------
// Kernel 2: MX-scaled fp8 MFMA GEMM  con[n,b] = sum_k cat[n,k]*x[b,k]
// R11-exact K-loop and epilogue (59.0us measured, all counters verified).
// R12 single change: __launch_bounds__(256, 3) — request 3 blocks/CU
// (2nd arg = waves/EU = blocks/CU at 256 thr). Resources fit: regs
// 76+64acc = 140 <= 512/3 = 170, LDS 3x32KB = 96 <= 160KB. Rationale:
// R9 vs R10 proved resident-block concurrency (m114 overlap) beats
// explicit pipelining for hiding the per-iter staging drain; we were
// running only 2 blocks/CU without asking for more.
// Layout recap (all HW-verified): granule-interleaved LDS slot =
// (r>>3)*64 + g*8 + (r&7); fragment k = quad*32+j; unit E8M0 scales;
// con stored fp8 [N/4, B, 4] packed dword per lane; pow4 on fp32 acc.
// ---------------------------------------------------------------------------
__global__ __launch_bounds__(256, 3) void gemm_bt_kernel(
    const unsigned char* __restrict__ A,    // cat fp8 [Ndim, Ddim]
    const unsigned char* __restrict__ Bm,   // x   fp8 [Bdim, Ddim]
    unsigned int* __restrict__ Cw,          // con fp8 [Ndim/4, Bdim, 4] as u32
    float* __restrict__ s4) {               // [Bdim] p4 column sums
  __shared__ unsigned char As[128 * 128];  // 16 KB, granule-interleaved
  __shared__ unsigned char Bs[128 * 128];  // 16 KB

  const int tid = threadIdx.x;
  const int wave = tid >> 6;
  const int lane = tid & 63;
  const int quad = lane >> 4;
  const int l16 = lane & 15;
  const int wm = (wave & 1) * 64;
  const int wn = (wave >> 1) * 64;
  const int m0 = blockIdx.x * 128;
  const int n0 = blockIdx.y * 128;

  floatx4 acc[4][4];
#pragma unroll
  for (int i = 0; i < 4; ++i)
#pragma unroll
    for (int j = 0; j < 4; ++j) acc[i][j] = (floatx4){0.f, 0.f, 0.f, 0.f};

  // staging: 1024 granule-slots per operand per K-iter; slot p holds
  // (row = (p>>6)*8 + (p&7), granule g = (p>>3)&7); 4 slots per thread.
  const unsigned char* a_src[4];
  const unsigned char* b_src[4];
#pragma unroll
  for (int i = 0; i < 4; ++i) {
    int p = tid + 256 * i;
    int row = ((p >> 6) << 3) + (p & 7);
    int colb = ((p >> 3) & 7) * 16;
    a_src[i] = A + (size_t)(m0 + row) * Ddim + colb;
    b_src[i] = Bm + (size_t)(n0 + row) * Ddim + colb;
  }

  for (int k0 = 0; k0 < Ddim; k0 += 128) {
#pragma unroll
    for (int i = 0; i < 4; ++i) {
      async_copy16(a_src[i] + k0, As + (tid + 256 * i) * 16);
      async_copy16(b_src[i] + k0, Bs + (tid + 256 * i) * 16);
    }
    __syncthreads();  // drains vmcnt before barrier

    // fragment: row r, k = quad*32..+31 = granules 2q,2q+1 ->
    // byte (r>>3)*1024 + quad*256 + (r&7)*16, and +128.
    int8v af[4], bf[4];
#pragma unroll
    for (int mi = 0; mi < 4; ++mi) {
      int r = wm + mi * 16 + l16;
      int base = ((r >> 3) << 10) + quad * 256 + (r & 7) * 16;
      int4v lo = *(const int4v*)(As + base);
      int4v hi = *(const int4v*)(As + base + 128);
      af[mi] = __builtin_shufflevector(lo, hi, 0, 1, 2, 3, 4, 5, 6, 7);
    }
#pragma unroll
    for (int ni = 0; ni < 4; ++ni) {
      int r = wn + ni * 16 + l16;
      int base = ((r >> 3) << 10) + quad * 256 + (r & 7) * 16;
      int4v lo = *(const int4v*)(Bs + base);
      int4v hi = *(const int4v*)(Bs + base + 128);
      bf[ni] = __builtin_shufflevector(lo, hi, 0, 1, 2, 3, 4, 5, 6, 7);
    }
#pragma unroll
    for (int mi = 0; mi < 4; ++mi)
#pragma unroll
      for (int ni = 0; ni < 4; ++ni)
        acc[mi][ni] = __builtin_amdgcn_mfma_scale_f32_16x16x128_f8f6f4(
            af[mi], bf[ni], acc[mi][ni], 0, 0,  // cbsz=0 (fp8), blgp=0 (fp8)
            0, 0x7f7f7f7f,                      // scale A: E8M0 1.0
            0, 0x7f7f7f7f);                     // scale B: E8M0 1.0
    __syncthreads();
  }

  // C/D layout (16x16): col = lane&15, row = quad*4 + reg [verified].
  // acc[..][0..3] = rows 4g..4g+3 of one column -> one packed u32 at
  // word index g*Bdim + col of the [N/4, B, 4] layout.
  float cs4[4] = {0.f, 0.f, 0.f, 0.f};
#pragma unroll
  for (int mi = 0; mi < 4; ++mi)
#pragma unroll
    for (int ni = 0; ni < 4; ++ni) {
      int g = (m0 + wm + mi * 16) / 4 + quad;  // n-group index
      int col = n0 + wn + ni * 16 + l16;
      floatx4 a = acc[mi][ni];
      int w = __builtin_amdgcn_cvt_pk_fp8_f32(a[0], a[1], 0, 0);
      w = __builtin_amdgcn_cvt_pk_fp8_f32(a[2], a[3], w, 1);
      Cw[(size_t)g * Bdim + col] = (unsigned int)w;
#pragma unroll
      for (int rr = 0; rr < 4; ++rr) {
        float c2 = a[rr] * a[rr];
        cs4[ni] += c2 * c2;  // pow4 on exact fp32 acc
      }
    }
#pragma unroll
  for (int ni = 0; ni < 4; ++ni) {
    float v = cs4[ni];
    v += __shfl_xor(v, 16);
    v += __shfl_xor(v, 32);
    if (quad == 0) atomicAdd(&s4[n0 + wn + ni * 16 + l16], v);
  }
}

// ---------------------------------------------------------------------------
// Kernel 3: denom[b] += sum exp(con/norm4); numer[s,b] += y-masked sum.
// Reads fp8 [N/4, B, 4] con: one u32 = 4 n-elements per thread per iter,
// lanes on consecutive b -> 256B/wave coalesced; y via wave-uniform int4.
// norm4 >= max|fp32 con|, fp8 quantization adds <=~7% -> logits <= ~1.07:
// no max-subtraction needed. grid (16, 32). 2 atomics per thread.
// ---------------------------------------------------------------------------
__global__ void expsum_kernel(const unsigned int* __restrict__ conq,
                              const float* __restrict__ s4,
                              const int* __restrict__ y,
                              float* __restrict__ denom,
                              float* __restrict__ numer) {
  int b = blockIdx.x * 256 + threadIdx.x;
  int g0 = blockIdx.y * 64;                 // n-group range [g0, g0+64)
  int src = (g0 * 4) / (Ndim / Sdim);       // uniform per block

  float inv = 1.0f / fmaxf(sqrtf(sqrtf(s4[b])), 1e-12f);
  const unsigned int* p = conq + (size_t)g0 * Bdim + b;
  float dsum = 0.f, nsum = 0.f;
#pragma unroll 4
  for (int i = 0; i < 64; ++i) {
    unsigned int w = p[(size_t)i * Bdim];
    int4 yv = *(const int4*)(y + 4 * (g0 + i));  // wave-uniform
    float e0 = __expf(__builtin_amdgcn_cvt_f32_fp8(w, 0) * inv);
    float e1 = __expf(__builtin_amdgcn_cvt_f32_fp8(w, 1) * inv);
    float e2 = __expf(__builtin_amdgcn_cvt_f32_fp8(w, 2) * inv);
    float e3 = __expf(__builtin_amdgcn_cvt_f32_fp8(w, 3) * inv);
    dsum += e0 + e1 + e2 + e3;
    nsum += e0 * (float)yv.x + e1 * (float)yv.y + e2 * (float)yv.z +
            e3 * (float)yv.w;
  }
  atomicAdd(&denom[b], dsum);
  atomicAdd(&numer[src * Bdim + b], nsum);
}

// ---------------------------------------------------------------------------
// Kernel 4 (tiny): out[b] = sigmoid(sum_s numer[s,b]*theta[s,b]/denom[b]+bias)
// ---------------------------------------------------------------------------
__global__ void finalize_kernel(const float* __restrict__ denom,
                                const float* __restrict__ numer,
                                const float* __restrict__ theta,
                                const float* __restrict__ bias,
                                float* __restrict__ out) {
  int b = blockIdx.x * 256 + threadIdx.x;
  float acc = 0.f;
#pragma unroll
  for (int si = 0; si < Sdim; ++si)
    acc += numer[si * Bdim + b] * theta[si * Bdim + b];
  float z = acc / denom[b] + bias[0];
  out[b] = 1.0f / (1.0f + __expf(-z));
}

// ---------------------------------------------------------------------------
// Workspace layout (bytes):
//   catq  : Ndim*Ddim     =  6,291,456   (fp8)
//   xq    : Bdim*Ddim     =  3,145,728   (fp8)
//   conq  : Ndim*Bdim     = 33,554,432   (fp8, [N/4, B, 4] interleaved)
//   stats : 6*Bdim*4      =     98,304   (s4 | denom | numer)
//   theta : Sdim*Bdim*4   =     65,536
//   total ≈ 43.2 MB
// ---------------------------------------------------------------------------
extern "C" void kernel_launch(void* const* d_in, const int* in_sizes, int n_in,
                              void* d_out, int out_size, void* d_ws,
                              size_t ws_size, hipStream_t stream) {
  const float* batch_x = (const float*)d_in[0];
  const float* cat = (const float*)d_in[1];
  const int* y = (const int*)d_in[2];
  const float* phi = (const float*)d_in[3];
  const float* bias = (const float*)d_in[4];
  float* out = (float*)d_out;

  char* ws = (char*)d_ws;
  unsigned char* catq = (unsigned char*)ws;
  unsigned char* xq = catq + (size_t)Ndim * Ddim;
  unsigned int* conq = (unsigned int*)(xq + (size_t)Bdim * Ddim);
  float* stats = (float*)((unsigned char*)conq + (size_t)Ndim * Bdim);
  float* s4 = stats;
  float* denom = s4 + Bdim;
  float* numer = denom + Bdim;        // Sdim * Bdim
  float* theta = stats + 6 * Bdim;    // Sdim * Bdim

  convert_kernel<<<2048, 256, 0, stream>>>(batch_x, cat, phi, xq, catq, stats,
                                           theta);

  dim3 g2(Ndim / 128, Bdim / 128);
  gemm_bt_kernel<<<g2, 256, 0, stream>>>(catq, xq, conq, s4);

  dim3 g3(Bdim / 256, 32);
  expsum_kernel<<<g3, 256, 0, stream>>>(conq, s4, y, denom, numer);

  finalize_kernel<<<Bdim / 256, 256, 0, stream>>>(denom, numer, theta, bias,
                                                  out);
}

// Round 13
// 155.781 us; speedup vs baseline: 1.1600x; 1.0080x over previous
//
#include <hip/hip_runtime.h>
#include <hip/hip_bf16.h>
#include <stdint.h>

// Problem constants (from reference): B=4096, D=768, N=8192, S=4
#define Bdim 4096
#define Ddim 768
#define Ndim 8192
#define Sdim 4

typedef __attribute__((ext_vector_type(4))) float floatx4;
typedef __attribute__((ext_vector_type(8))) int int8v;
typedef __attribute__((ext_vector_type(4))) int int4v;

// pack float4 -> 4x fp8 e4m3 (OCP on gfx950), HW RNE
__device__ inline int pack_fp8x4(float4 v) {
  int r = __builtin_amdgcn_cvt_pk_fp8_f32(v.x, v.y, 0, 0);  // low word
  r = __builtin_amdgcn_cvt_pk_fp8_f32(v.z, v.w, r, 1);      // high word
  return r;
}

// ---------------------------------------------------------------------------
// Kernel 1: fp32 -> fp8 e4m3 quantization of batch_x and cat; zero the stats
// region; theta[s,b] = exp(batch_x[b].phi[s]) in fp32 (one wave per b).
// stats = [s4 (B) | denom (B) | numer (S*B)] floats
// ---------------------------------------------------------------------------
__global__ void convert_kernel(const float* __restrict__ x,
                               const float* __restrict__ cat,
                               const float* __restrict__ phi,
                               unsigned char* __restrict__ xq,
                               unsigned char* __restrict__ catq,
                               float* __restrict__ stats,
                               float* __restrict__ theta) {
  int gid = blockIdx.x * blockDim.x + threadIdx.x;
  int stride = gridDim.x * blockDim.x;
  const int nx4 = (Bdim * Ddim) / 4;
  const int nc4 = (Ndim * Ddim) / 4;
  for (int i = gid; i < nx4; i += stride)
    ((int*)xq)[i] = pack_fp8x4(((const float4*)x)[i]);
  for (int i = gid; i < nc4; i += stride)
    ((int*)catq)[i] = pack_fp8x4(((const float4*)cat)[i]);
  if (gid < 6 * Bdim) stats[gid] = 0.0f;

  // theta: one wave per batch row (fp32 — exact path, output-critical)
  int gw = gid >> 6;
  int lane = threadIdx.x & 63;
  if (gw < Bdim) {
    const float* xr = x + (size_t)gw * Ddim;
    float a0 = 0.f, a1 = 0.f, a2 = 0.f, a3 = 0.f;
    for (int d = lane; d < Ddim; d += 64) {
      float xv = xr[d];
      a0 = fmaf(xv, phi[d], a0);
      a1 = fmaf(xv, phi[Ddim + d], a1);
      a2 = fmaf(xv, phi[2 * Ddim + d], a2);
      a3 = fmaf(xv, phi[3 * Ddim + d], a3);
    }
#pragma unroll
    for (int off = 32; off > 0; off >>= 1) {
      a0 += __shfl_down(a0, off);
      a1 += __shfl_down(a1, off);
      a2 += __shfl_down(a2, off);
      a3 += __shfl_down(a3, off);
    }
    if (lane == 0) {
      theta[gw] = __expf(a0);
      theta[Bdim + gw] = __expf(a1);
      theta[2 * Bdim + gw] = __expf(a2);
      theta[3 * Bdim + gw] = __expf(a3);
    }
  }
}

// ---------------------------------------------------------------------------
// Kernel 2: MX-scaled fp8 MFMA GEMM  con[n,b] = sum_k cat[n,k]*x[b,k]
// R13: REGISTER-PREFETCH pipeline. R9/R11's structure exposed the full
// ~900cyc VMEM latency every iter (loads issued immediately before the
// barrier's vmcnt drain); with the 2-blocks/CU cap (R12: launch_bounds
// can't raise it; R10: dbuf LDS trade loses) the neighbor block can't
// cover it. Fix that costs NO LDS and NO occupancy (we're reg-free at 2
// waves/SIMD): tile k+1 -> VGPRs (8x global_load_dwordx4, +32 reg) issued
// BEFORE compute of tile k; after the read-barrier, ds_write_b128 the regs
// into the same single 16KB buffers; second barrier; repeat. Compiler's
// auto vmcnt(0) at barrier-1 now waits only latency-minus-compute.
// Everything else R11-exact (verified): granule-interleaved LDS slot =
// (r>>3)*64 + g*8 + (r&7); fragment k = quad*32+j; unit E8M0 scales;
// con stored fp8 [N/4, B, 4] packed dword; pow4 on fp32 acc; natural grid.
// ---------------------------------------------------------------------------
__global__ __launch_bounds__(256) void gemm_bt_kernel(
    const unsigned char* __restrict__ A,    // cat fp8 [Ndim, Ddim]
    const unsigned char* __restrict__ Bm,   // x   fp8 [Bdim, Ddim]
    unsigned int* __restrict__ Cw,          // con fp8 [Ndim/4, Bdim, 4] as u32
    float* __restrict__ s4) {               // [Bdim] p4 column sums
  __shared__ unsigned char As[128 * 128];  // 16 KB, granule-interleaved
  __shared__ unsigned char Bs[128 * 128];  // 16 KB

  const int tid = threadIdx.x;
  const int wave = tid >> 6;
  const int lane = tid & 63;
  const int quad = lane >> 4;
  const int l16 = lane & 15;
  const int wm = (wave & 1) * 64;
  const int wn = (wave >> 1) * 64;
  const int m0 = blockIdx.x * 128;
  const int n0 = blockIdx.y * 128;

  floatx4 acc[4][4];
#pragma unroll
  for (int i = 0; i < 4; ++i)
#pragma unroll
    for (int j = 0; j < 4; ++j) acc[i][j] = (floatx4){0.f, 0.f, 0.f, 0.f};

  // staging: 1024 granule-slots per operand per K-tile; slot p holds
  // (row = (p>>6)*8 + (p&7), granule g = (p>>3)&7); 4 slots per thread.
  const unsigned char* a_src[4];
  const unsigned char* b_src[4];
#pragma unroll
  for (int i = 0; i < 4; ++i) {
    int p = tid + 256 * i;
    int row = ((p >> 6) << 3) + (p & 7);
    int colb = ((p >> 3) & 7) * 16;
    a_src[i] = A + (size_t)(m0 + row) * Ddim + colb;
    b_src[i] = Bm + (size_t)(n0 + row) * Ddim + colb;
  }

  // prologue: tile 0 -> regs -> LDS (latency exposed once, not per-iter)
  int4v areg[4], breg[4];
#pragma unroll
  for (int i = 0; i < 4; ++i) {
    areg[i] = *(const int4v*)(a_src[i]);
    breg[i] = *(const int4v*)(b_src[i]);
  }
#pragma unroll
  for (int i = 0; i < 4; ++i) {
    *(int4v*)(As + (tid + 256 * i) * 16) = areg[i];
    *(int4v*)(Bs + (tid + 256 * i) * 16) = breg[i];
  }
  __syncthreads();

  for (int kk = 0; kk < 6; ++kk) {
    if (kk < 5) {
      const int k0 = (kk + 1) * 128;
      // prefetch next tile into VGPRs; whole compute phase hides latency
#pragma unroll
      for (int i = 0; i < 4; ++i) {
        areg[i] = *(const int4v*)(a_src[i] + k0);
        breg[i] = *(const int4v*)(b_src[i] + k0);
      }
    }

    // compute current tile from LDS.
    // fragment: row r, k = quad*32..+31 = granules 2q,2q+1 ->
    // byte (r>>3)*1024 + quad*256 + (r&7)*16, and +128.
    int8v af[4], bf[4];
#pragma unroll
    for (int mi = 0; mi < 4; ++mi) {
      int r = wm + mi * 16 + l16;
      int base = ((r >> 3) << 10) + quad * 256 + (r & 7) * 16;
      int4v lo = *(const int4v*)(As + base);
      int4v hi = *(const int4v*)(As + base + 128);
      af[mi] = __builtin_shufflevector(lo, hi, 0, 1, 2, 3, 4, 5, 6, 7);
    }
#pragma unroll
    for (int ni = 0; ni < 4; ++ni) {
      int r = wn + ni * 16 + l16;
      int base = ((r >> 3) << 10) + quad * 256 + (r & 7) * 16;
      int4v lo = *(const int4v*)(Bs + base);
      int4v hi = *(const int4v*)(Bs + base + 128);
      bf[ni] = __builtin_shufflevector(lo, hi, 0, 1, 2, 3, 4, 5, 6, 7);
    }
#pragma unroll
    for (int mi = 0; mi < 4; ++mi)
#pragma unroll
      for (int ni = 0; ni < 4; ++ni)
        acc[mi][ni] = __builtin_amdgcn_mfma_scale_f32_16x16x128_f8f6f4(
            af[mi], bf[ni], acc[mi][ni], 0, 0,  // cbsz=0 (fp8), blgp=0 (fp8)
            0, 0x7f7f7f7f,                      // scale A: E8M0 1.0
            0, 0x7f7f7f7f);                     // scale B: E8M0 1.0

    __syncthreads();  // all reads of the tile done (residual vmcnt drain)

    if (kk < 5) {
#pragma unroll
      for (int i = 0; i < 4; ++i) {
        *(int4v*)(As + (tid + 256 * i) * 16) = areg[i];
        *(int4v*)(Bs + (tid + 256 * i) * 16) = breg[i];
      }
      __syncthreads();  // LDS ready for next iter
    }
  }

  // C/D layout (16x16): col = lane&15, row = quad*4 + reg [verified].
  // acc[..][0..3] = rows 4g..4g+3 of one column -> one packed u32 at
  // word index g*Bdim + col of the [N/4, B, 4] layout.
  float cs4[4] = {0.f, 0.f, 0.f, 0.f};
#pragma unroll
  for (int mi = 0; mi < 4; ++mi)
#pragma unroll
    for (int ni = 0; ni < 4; ++ni) {
      int g = (m0 + wm + mi * 16) / 4 + quad;  // n-group index
      int col = n0 + wn + ni * 16 + l16;
      floatx4 a = acc[mi][ni];
      int w = __builtin_amdgcn_cvt_pk_fp8_f32(a[0], a[1], 0, 0);
      w = __builtin_amdgcn_cvt_pk_fp8_f32(a[2], a[3], w, 1);
      Cw[(size_t)g * Bdim + col] = (unsigned int)w;
#pragma unroll
      for (int rr = 0; rr < 4; ++rr) {
        float c2 = a[rr] * a[rr];
        cs4[ni] += c2 * c2;  // pow4 on exact fp32 acc
      }
    }
#pragma unroll
  for (int ni = 0; ni < 4; ++ni) {
    float v = cs4[ni];
    v += __shfl_xor(v, 16);
    v += __shfl_xor(v, 32);
    if (quad == 0) atomicAdd(&s4[n0 + wn + ni * 16 + l16], v);
  }
}

// ---------------------------------------------------------------------------
// Kernel 3: denom[b] += sum exp(con/norm4); numer[s,b] += y-masked sum.
// Reads fp8 [N/4, B, 4] con: one u32 = 4 n-elements per thread per iter,
// lanes on consecutive b -> 256B/wave coalesced; y via wave-uniform int4.
// norm4 >= max|fp32 con|, fp8 quantization adds <=~7% -> logits <= ~1.07:
// no max-subtraction needed. grid (16, 32). 2 atomics per thread.
// ---------------------------------------------------------------------------
__global__ void expsum_kernel(const unsigned int* __restrict__ conq,
                              const float* __restrict__ s4,
                              const int* __restrict__ y,
                              float* __restrict__ denom,
                              float* __restrict__ numer) {
  int b = blockIdx.x * 256 + threadIdx.x;
  int g0 = blockIdx.y * 64;                 // n-group range [g0, g0+64)
  int src = (g0 * 4) / (Ndim / Sdim);       // uniform per block

  float inv = 1.0f / fmaxf(sqrtf(sqrtf(s4[b])), 1e-12f);
  const unsigned int* p = conq + (size_t)g0 * Bdim + b;
  float dsum = 0.f, nsum = 0.f;
#pragma unroll 4
  for (int i = 0; i < 64; ++i) {
    unsigned int w = p[(size_t)i * Bdim];
    int4 yv = *(const int4*)(y + 4 * (g0 + i));  // wave-uniform
    float e0 = __expf(__builtin_amdgcn_cvt_f32_fp8(w, 0) * inv);
    float e1 = __expf(__builtin_amdgcn_cvt_f32_fp8(w, 1) * inv);
    float e2 = __expf(__builtin_amdgcn_cvt_f32_fp8(w, 2) * inv);
    float e3 = __expf(__builtin_amdgcn_cvt_f32_fp8(w, 3) * inv);
    dsum += e0 + e1 + e2 + e3;
    nsum += e0 * (float)yv.x + e1 * (float)yv.y + e2 * (float)yv.z +
            e3 * (float)yv.w;
  }
  atomicAdd(&denom[b], dsum);
  atomicAdd(&numer[src * Bdim + b], nsum);
}

// ---------------------------------------------------------------------------
// Kernel 4 (tiny): out[b] = sigmoid(sum_s numer[s,b]*theta[s,b]/denom[b]+bias)
// ---------------------------------------------------------------------------
__global__ void finalize_kernel(const float* __restrict__ denom,
                                const float* __restrict__ numer,
                                const float* __restrict__ theta,
                                const float* __restrict__ bias,
                                float* __restrict__ out) {
  int b = blockIdx.x * 256 + threadIdx.x;
  float acc = 0.f;
#pragma unroll
  for (int si = 0; si < Sdim; ++si)
    acc += numer[si * Bdim + b] * theta[si * Bdim + b];
  float z = acc / denom[b] + bias[0];
  out[b] = 1.0f / (1.0f + __expf(-z));
}

// ---------------------------------------------------------------------------
// Workspace layout (bytes):
//   catq  : Ndim*Ddim     =  6,291,456   (fp8)
//   xq    : Bdim*Ddim     =  3,145,728   (fp8)
//   conq  : Ndim*Bdim     = 33,554,432   (fp8, [N/4, B, 4] interleaved)
//   stats : 6*Bdim*4      =     98,304   (s4 | denom | numer)
//   theta : Sdim*Bdim*4   =     65,536
//   total ≈ 43.2 MB
// ---------------------------------------------------------------------------
extern "C" void kernel_launch(void* const* d_in, const int* in_sizes, int n_in,
                              void* d_out, int out_size, void* d_ws,
                              size_t ws_size, hipStream_t stream) {
  const float* batch_x = (const float*)d_in[0];
  const float* cat = (const float*)d_in[1];
  const int* y = (const int*)d_in[2];
  const float* phi = (const float*)d_in[3];
  const float* bias = (const float*)d_in[4];
  float* out = (float*)d_out;

  char* ws = (char*)d_ws;
  unsigned char* catq = (unsigned char*)ws;
  unsigned char* xq = catq + (size_t)Ndim * Ddim;
  unsigned int* conq = (unsigned int*)(xq + (size_t)Bdim * Ddim);
  float* stats = (float*)((unsigned char*)conq + (size_t)Ndim * Bdim);
  float* s4 = stats;
  float* denom = s4 + Bdim;
  float* numer = denom + Bdim;        // Sdim * Bdim
  float* theta = stats + 6 * Bdim;    // Sdim * Bdim

  convert_kernel<<<2048, 256, 0, stream>>>(batch_x, cat, phi, xq, catq, stats,
                                           theta);

  dim3 g2(Ndim / 128, Bdim / 128);
  gemm_bt_kernel<<<g2, 256, 0, stream>>>(catq, xq, conq, s4);

  dim3 g3(Bdim / 256, 32);
  expsum_kernel<<<g3, 256, 0, stream>>>(conq, s4, y, denom, numer);

  finalize_kernel<<<Bdim / 256, 256, 0, stream>>>(denom, numer, theta, bias,
                                                  out);
}